// Round 5
// baseline (61.758 us; speedup 1.0000x reference)
//
#include <hip/hip_runtime.h>
#include <cmath>

// x: (512,128) fp32. Per column: sort 512; reference computes a 999-pt trapezoid
// of the Beta(0.6,0.4) pdf from x1=EPS+h to s (h=(s-EPS)/999, t=0 dropped);
// loss = sum((pcdf-ecdf)^2)/512, threshold 4.875e-2 absolute.
//
//   T(s) = I_s(0.6,0.4)  - c_head2*s^0.6  + D_R(2 intervals, telescoped)
//
// R1: rank-by-counting regressed -> bitonic sort kept.
// R2: branchless single betacf: -2.8 us.
// R3: fused atomic output (node overhead ~0.5us, not 10); CF 16->6: -1 us.
// R4: CF 6->4, D_R 8->4 telescoped: -2.4 us. Decomposition: ~39.6us poison fill
//     (harness, HBM-bound) + ~19us fixed reset dispatches + ~3us kernel.
// R5: (a) CF divides eliminated: aa-denominators are per-branch compile-time
//         constants; 1/d,1/c via v_rcp (1ulp). Without -ffast-math each '/' was
//         a ~10-instr IEEE div sequence -> 24 divides ~ 240 serial instrs gone.
//         Lentz clamps dropped (d,c provably in [0.73,1.6] for x<=0.5333).
//     (b) sort cross-wave stages double-buffered: 1 barrier/stage (13->7).
//     (c) head via c_head2*exp(0.6*ls) (x1~s/999, err<1e-6); D_R 4->2 intervals
//         (worst-element residual +1.3e-4, budget ~1.9e-3).
#define N_ROWS 512
#define N_COLS 128

__device__ __forceinline__ float rcpf(float v) { return __builtin_amdgcn_rcpf(v); }

// -------- Single kernel: bitonic sort + per-element pcdf-loss + atomic out --
__global__ __launch_bounds__(512) void sort_loss(const float* __restrict__ x,
                                                 float* __restrict__ out,
                                                 float lnB, float invB, float c_head2) {
    __shared__ float sdA[N_ROWS];
    __shared__ float sdB[N_ROWS];
    const int tid = threadIdx.x;
    const int col = blockIdx.x;
    float v = x[tid * N_COLS + col];

    // Bitonic sort. Cross-wave stages ping-pong between sdA/sdB so ONE barrier
    // per stage suffices: stage-n reads of a buffer all precede barrier n+1,
    // and the next write to that buffer follows it.
    float* buf = sdA;
    for (int k = 2; k <= N_ROWS; k <<= 1) {
        for (int j = k >> 1; j > 0; j >>= 1) {
            float pv;
            if (j >= 64) {                 // cross-wave via LDS (6 stages total)
                buf[tid] = v;
                __syncthreads();
                pv = buf[tid ^ j];
                buf = (buf == sdA) ? sdB : sdA;
            } else {                       // in-wave: shuffle
                pv = __shfl_xor(v, j, 64);
            }
            const bool lower = (tid & j) == 0;
            const bool asc   = (tid & k) == 0;
            v = (lower == asc) ? fminf(v, pv) : fmaxf(v, pv);
        }
    }
    // v = sorted value at rank `tid` of column `col`.
    const float s  = fmaxf(v, 1e-30f);
    const float sm = s - 1e-10f;
    const float h  = sm * (1.0f / 999.0f);

    const float ls  = __logf(s);
    const float om  = fmaxf(1.0f - s, 1e-30f);
    const float lom = __logf(om);
    const float bt  = __expf(fmaf(0.6f, ls, fmaf(0.4f, lom, -lnB)));

    // ---- regularized incomplete beta via Lentz CF, division-free ----------
    // Branch constants: lo -> (a,b)=(0.6,0.4), x=s ; hi -> (0.4,0.6), x=om.
    // C_m = m(b-m)/((a-1+2m)(a+2m)) [even halves], -(a+m)(1+m)/((a+2m)(a+1+2m)) [odd].
    const bool  lo = s < 0.53333333f;
    const float cx = lo ? s : om;
    const float r0 = lo ? 0.625f       : 0.71428573f;   // 1/(a+1)
    const float e1 = lo ? -0.14423077f : -0.11904762f;
    const float o1 = lo ? -0.34188035f : -0.34313726f;
    const float e2 = lo ? -0.19323671f : -0.18716577f;
    const float o2 = lo ? -0.30279503f : -0.30303031f;
    const float e3 = lo ? -0.21103896f : -0.20833333f;
    const float o3 = lo ? -0.28708133f : -0.28716215f;
    const float e4 = lo ? -0.22031824f : -0.21879020f;
    const float o4 = lo ? -0.27858528f : -0.27862209f;

    float rd  = rcpf(fmaf(-r0, cx, 1.0f));   // 1/d0
    float hcf = rd;
    float cr  = 1.0f;                        // 1/c
    // |aa| <= 0.19, so d,c stay in [0.73,1.6]: no underflow clamps needed.
    #define CF_HALF(COEF) { \
        const float aa = (COEF) * cx; \
        const float dn = fmaf(aa, rd, 1.0f); rd = rcpf(dn); \
        const float cn = fmaf(aa, cr, 1.0f); cr = rcpf(cn); \
        hcf *= rd * cn; }
    CF_HALF(e1) CF_HALF(o1) CF_HALF(e2) CF_HALF(o2)
    CF_HALF(e3) CF_HALF(o3) CF_HALF(e4) CF_HALF(o4)
    #undef CF_HALF

    const float I = lo ? bt * hcf * 1.6666667f
                       : 1.0f - bt * hcf * 2.5f;

    // head correction: c_head2 * s^0.6  (x1 ~ s/999 folded into c_head2)
    const float head = c_head2 * __expf(0.6f * ls);

    // right-end trap-minus-exact, last 2 intervals, telescoped:
    // D_R = s^-0.4/B * [ h*(f0/2 + f1 + f2/2) - (w2^0.4 - w0^0.4)*2.5 ]
    const float sm04 = __expf(-0.4f * ls);             // s^{-0.4}
    const float f0   = __expf(-0.6f * lom);            // om^{-0.6}
    const float w1   = om + h;
    const float f1   = __expf(-0.6f * __logf(w1));
    const float w2   = fmaf(2.0f, h, om);
    const float f2   = __expf(-0.6f * __logf(w2));
    const float fsum = fmaf(0.5f, f0 + f2, f1);
    const float drc  = (h * fsum - (w2 * f2 - om * f0) * 2.5f) * sm04 * invB;

    const float T    = I - head + drc;
    const float ecdf = (float)(tid + 1) * (1.0f / 513.0f);
    const float d    = T - ecdf;
    float val = d * d;

    // block reduction (8 waves)
    #pragma unroll
    for (int off = 32; off > 0; off >>= 1)
        val += __shfl_down(val, off);
    // sdA free: its last reads (stage 5) completed before stage-6's barrier.
    if ((tid & 63) == 0) sdA[tid >> 6] = val;
    __syncthreads();
    if (tid == 0) {
        float bs = 0.0f;
        #pragma unroll
        for (int w = 0; w < 8; ++w) bs += sdA[w];
        atomicAdd(out, bs * (1.0f / (float)N_ROWS));   // out pre-zeroed by memset node
    }
}

extern "C" void kernel_launch(void* const* d_in, const int* in_sizes, int n_in,
                              void* d_out, int out_size, void* d_ws, size_t ws_size,
                              hipStream_t stream) {
    const float* x = (const float*)d_in[0];
    float* out = (float*)d_out;

    const double B = exp(lgamma(0.6) + lgamma(0.4) - lgamma(1.0));  // 3.3034443
    const float lnB    = (float)log(B);
    const float invB   = (float)(1.0 / B);
    // head coeff: (1/(0.6B) - 0.03185/B) * 999^-0.6   (x1 ~ s/999 absorbed)
    const float c_head2 = (float)((1.0 / (0.6 * B) - 0.03185 / B) * pow(999.0, -0.6));

    hipMemsetAsync(d_out, 0, sizeof(float), stream);
    sort_loss<<<N_COLS, N_ROWS, 0, stream>>>(x, out, lnB, invB, c_head2);
}